// Round 6
// baseline (647.708 us; speedup 1.0000x reference)
//
#include <hip/hip_runtime.h>

// SOMNetwork forward. All four rbf/cdist layers via split-bf16 MFMA GEMM
// (hi/lo decomposition, 3 MFMAs/product). L1: patch extraction fused into the
// GEMM blocks (raw images -> LDS -> hi/lo A-tile in LDS, no P matrix),
// two-pass (std reduce, then fused exp/crelu/2x2-pool epilogue).
// L2/L3/L4: 256x256-tile 8-wave GEMM (halves LDS staging traffic vs 128x128),
// dist buffer holds squared distances. Channels batched into grid z.

typedef unsigned short u16;
typedef short bf16x8 __attribute__((ext_vector_type(8)));
typedef float f32x4 __attribute__((ext_vector_type(4)));

#define STRIPES 64
#define ACC_L2 0            // 64 stripes * 2 doubles per layer region
#define ACC_L3 128
#define ACC_L4 256
#define ACC_TOTAL 384
#define ESM_P 132

__device__ __forceinline__ u16 f2bf(float f) {
  unsigned int u = __float_as_uint(f);
  unsigned int r = (u + 0x7fffu + ((u >> 16) & 1u)) >> 16;
  return (u16)r;
}
__device__ __forceinline__ float bf2f(u16 h) {
  return __uint_as_float(((unsigned int)h) << 16);
}
__device__ __forceinline__ void gload16(const void* g, const void* l) {
  __builtin_amdgcn_global_load_lds(
      (const __attribute__((address_space(1))) unsigned int*)g,
      (__attribute__((address_space(3))) unsigned int*)l, 16, 0, 0);
}

__global__ void zero_acc_kernel(double* __restrict__ acc, int n) {
  int i = blockIdx.x * blockDim.x + threadIdx.x;
  if (i < n) acc[i] = 0.0;
}

// ---------------- weight prep: fp32 -> hi/lo bf16 (padded) + row norms ----------------
__global__ __launch_bounds__(128) void w_prep(
    const float* __restrict__ W, int O, int K, int Opad, int Kp,
    u16* __restrict__ hi, u16* __restrict__ lo, float* __restrict__ wn)
{
  __shared__ float red[2];
  int o = blockIdx.x, cc = blockIdx.y, t = threadIdx.x;
  const float* src = W + ((size_t)cc * O + o) * K;
  u16* dh = hi + ((size_t)cc * Opad + o) * Kp;
  u16* dl = lo + ((size_t)cc * Opad + o) * Kp;
  float p = 0.f;
  for (int k = t; k < Kp; k += 128) {
    float v = (o < O && k < K) ? src[k] : 0.f;
    u16 h = f2bf(v);
    u16 l = f2bf(v - bf2f(h));
    dh[k] = h; dl[k] = l;
    p = fmaf(v, v, p);
  }
  for (int off = 32; off; off >>= 1) p += __shfl_down(p, off, 64);
  if ((t & 63) == 0) red[t >> 6] = p;
  __syncthreads();
  if (t == 0) wn[(size_t)cc * Opad + o] = red[0] + red[1];
}

// ---------------- L1 shared mainloop: fused patch extraction + MFMA ----------------
// sm layout (u16): Ah[0..4095] Al[4096..8191] Bh[8192..12287] Bl[12288..16383]
// A slot = (q*128 + row)*8 ; rows = 2 images x 64 (patch rows 0..35 valid)
__device__ __forceinline__ void l1_mainloop(
    const float* __restrict__ x, int b0, int c,
    const u16* __restrict__ Wh, const u16* __restrict__ Wl,
    u16* sm, float* img, float* pnsm, float* pnloc, f32x4 (&accv)[4][4])
{
  const int t = threadIdx.x;
  const int w = t >> 6, lane = t & 63;
  // B staging (async): wave w stages k-chunk q=w, rows 0..127
  {
    const int kk = (w & 3) * 8;
#pragma unroll
    for (int u = 0; u < 2; ++u) {
      const size_t gb = (size_t)(u * 64 + lane) * 32 + kk;
      const int ls = ((w & 3) * 128 + u * 64) * 8;
      gload16(Wh + gb, sm + 8192 + ls);
      gload16(Wl + gb, sm + 12288 + ls);
    }
  }
  // raw images -> LDS
#pragma unroll
  for (int im = 0; im < 2; ++im) {
    if (t < 196)
      ((float4*)(img + im * 784))[t] =
          ((const float4*)(x + ((size_t)(b0 + im) * 3 + c) * 784))[t];
  }
  __syncthreads();
  // extraction: 512 A-slots, hi/lo conversion + pnorm partials
  for (int s = t; s < 512; s += 256) {
    int q = s >> 7, row = s & 127;
    int im = row >> 6, pr = row & 63;
    int pi = pr / 6, pj = pr - pi * 6;
    const float* ib = img + im * 784 + pi * 4 * 28 + pj * 4;
    float v[8]; float pn = 0.f;
#pragma unroll
    for (int e = 0; e < 8; ++e) {
      int k = q * 8 + e;
      float val = 0.f;
      if (pr < 36 && k < 25) { int r = k / 5, ss = k - r * 5; val = ib[r * 28 + ss]; }
      v[e] = val; pn = fmaf(val, val, pn);
    }
    u16 hi8[8], lo8[8];
#pragma unroll
    for (int e = 0; e < 8; ++e) {
      u16 h = f2bf(v[e]); hi8[e] = h; lo8[e] = f2bf(v[e] - bf2f(h));
    }
    *(bf16x8*)(sm + (q * 128 + row) * 8) = *(bf16x8*)hi8;
    *(bf16x8*)(sm + 4096 + (q * 128 + row) * 8) = *(bf16x8*)lo8;
    pnsm[s] = pn;
  }
  asm volatile("s_waitcnt vmcnt(0)" ::: "memory");
  __syncthreads();
  if (t < 128) pnloc[t] = pnsm[t] + pnsm[128 + t] + pnsm[256 + t] + pnsm[384 + t];

  const int wr = w >> 1, wc = w & 1;
  const int q4 = lane >> 4, r16 = lane & 15;
  bf16x8 Ah[4], Al[4], Bh[4], Bl[4];
#pragma unroll
  for (int i = 0; i < 4; ++i) {
    int ao = (q4 * 128 + wr * 64 + i * 16 + r16) * 8;
    int bo = (q4 * 128 + wc * 64 + i * 16 + r16) * 8;
    Ah[i] = *(const bf16x8*)(sm + ao);
    Al[i] = *(const bf16x8*)(sm + 4096 + ao);
    Bh[i] = *(const bf16x8*)(sm + 8192 + bo);
    Bl[i] = *(const bf16x8*)(sm + 12288 + bo);
  }
#pragma unroll
  for (int i = 0; i < 4; ++i)
#pragma unroll
    for (int j = 0; j < 4; ++j) {
      accv[i][j] = __builtin_amdgcn_mfma_f32_16x16x32_bf16(Ah[i], Bh[j], accv[i][j], 0, 0, 0);
      accv[i][j] = __builtin_amdgcn_mfma_f32_16x16x32_bf16(Al[i], Bh[j], accv[i][j], 0, 0, 0);
      accv[i][j] = __builtin_amdgcn_mfma_f32_16x16x32_bf16(Ah[i], Bl[j], accv[i][j], 0, 0, 0);
    }
  __syncthreads();   // pnloc visible to epilogue
}

// ---------------- L1 pass A: per-position s/q -> per-block float partials ----------------
__global__ __launch_bounds__(256) void l1_gemm_reduce(
    const float* __restrict__ x, const u16* __restrict__ W1h, const u16* __restrict__ W1l,
    const float* __restrict__ w1n, float* __restrict__ part, int NB, int c0, int sPartc)
{
  __shared__ __align__(16) u16 sm[16384];
  __shared__ float img[1568];
  __shared__ float pnsm[512];
  __shared__ float pnloc[128];
  __shared__ float sq[72];
  int t = threadIdx.x, zi = blockIdx.y, c = c0 + zi;
  const u16* Wh = W1h + (size_t)c * 4096;
  const u16* Wl = W1l + (size_t)c * 4096;
  const float* wn = w1n + (size_t)c * 128;
  part += (size_t)zi * sPartc;
  if (t < 72) sq[t] = 0.f;
  f32x4 accv[4][4];
#pragma unroll
  for (int i = 0; i < 4; ++i)
#pragma unroll
    for (int j = 0; j < 4; ++j) accv[i][j] = (f32x4){0.f, 0.f, 0.f, 0.f};
  const int b0 = blockIdx.x * 2;
  l1_mainloop(x, b0, c, Wh, Wl, sm, img, pnsm, pnloc, accv);

  const int w = t >> 6, lane = t & 63;
  const int wr = w >> 1, wc = w & 1, q4 = lane >> 4, r16 = lane & 15;
#pragma unroll
  for (int i = 0; i < 4; ++i) {
#pragma unroll
    for (int r = 0; r < 4; ++r) {
      int pos = i * 16 + q4 * 4 + r;
      if (pos < 36) {
        float pn = pnloc[wr * 64 + pos];
        float s = 0.f, q = 0.f;
#pragma unroll
        for (int j = 0; j < 4; ++j) {
          int col = wc * 64 + j * 16 + r16;
          if (col < 100) {
            float d2 = pn + wn[col] - 2.f * accv[i][j][r];
            float d2c = fmaxf(d2, 0.f) + 1e-12f;
            s += sqrtf(d2c);
            q += d2c;
          }
        }
        s += __shfl_down(s, 8, 16);
        s += __shfl_down(s, 4, 16);
        s += __shfl_down(s, 2, 16);
        s += __shfl_down(s, 1, 16);
        q += __shfl_down(q, 8, 16);
        q += __shfl_down(q, 4, 16);
        q += __shfl_down(q, 2, 16);
        q += __shfl_down(q, 1, 16);
        if (r16 == 0) {
          atomicAdd(&sq[pos], s);
          atomicAdd(&sq[36 + pos], q);
        }
      }
    }
  }
  __syncthreads();
  if (t < 72) part[(size_t)t * NB + blockIdx.x] = sq[t];
}

__global__ __launch_bounds__(256) void l1_part_fin(
    const float* __restrict__ part, int NB, float* __restrict__ inv36, double n,
    int sPartc, int sInvc)
{
  __shared__ double sh[8];
  int pos = blockIdx.x, zi = blockIdx.y, t = threadIdx.x;
  part += (size_t)zi * sPartc; inv36 += (size_t)zi * sInvc;
  double s = 0.0, q = 0.0;
  for (int b = t; b < NB; b += 256) {
    s += part[(size_t)pos * NB + b];
    q += part[(size_t)(36 + pos) * NB + b];
  }
  for (int off = 32; off; off >>= 1) {
    s += __shfl_down(s, off, 64);
    q += __shfl_down(q, off, 64);
  }
  if ((t & 63) == 0) { sh[(t >> 6) * 2] = s; sh[(t >> 6) * 2 + 1] = q; }
  __syncthreads();
  if (t == 0) {
    s = sh[0] + sh[2] + sh[4] + sh[6];
    q = sh[1] + sh[3] + sh[5] + sh[7];
    double var = (q - s * s / n) / (n - 1.0);
    inv36[pos] = var > 0.0 ? (float)(0.5 / var) : __builtin_inff();
  }
}

// ---------------- L1 pass B: fused exp/crelu/2x2-alpha-pool epilogue ----------------
__global__ __launch_bounds__(256) void l1_gemm_sfm(
    const float* __restrict__ x, const u16* __restrict__ W1h, const u16* __restrict__ W1l,
    const float* __restrict__ w1n, const float* __restrict__ inv36,
    const float* __restrict__ cb,
    u16* __restrict__ Xhi, u16* __restrict__ Xlo, float* __restrict__ xn,
    int c0, int sInvc, int sXc, int sxnc)
{
  __shared__ __align__(16) u16 sm[16384];
  __shared__ float img[1568];
  __shared__ float pnsm[512];
  __shared__ float pnloc[128];
  __shared__ float psm[2 * 18 * ESM_P];
  __shared__ float inv_s[36];
  int t = threadIdx.x, zi = blockIdx.y, c = c0 + zi;
  const u16* Wh = W1h + (size_t)c * 4096;
  const u16* Wl = W1l + (size_t)c * 4096;
  const float* wn = w1n + (size_t)c * 128;
  inv36 += (size_t)zi * sInvc;
  Xhi += (size_t)zi * sXc; Xlo += (size_t)zi * sXc; xn += (size_t)zi * sxnc;
  if (t < 36) inv_s[t] = inv36[t];
  f32x4 accv[4][4];
#pragma unroll
  for (int i = 0; i < 4; ++i)
#pragma unroll
    for (int j = 0; j < 4; ++j) accv[i][j] = (f32x4){0.f, 0.f, 0.f, 0.f};
  const int b0 = blockIdx.x * 2;
  l1_mainloop(x, b0, c, Wh, Wl, sm, img, pnsm, pnloc, accv);

  const float bias = cb[0];
  const int w = t >> 6, lane = t & 63;
  const int wr = w >> 1, wc = w & 1, q4 = lane >> 4, r16 = lane & 15;
#pragma unroll
  for (int i = 0; i < 4; ++i) {
#pragma unroll
    for (int j = 0; j < 4; ++j) {
      int col = wc * 64 + j * 16 + r16;
      float e[4];
#pragma unroll
      for (int r = 0; r < 4; ++r) {
        int pos = i * 16 + q4 * 4 + r;
        float ev = 0.f;
        if (pos < 36) {
          float pn = pnloc[wr * 64 + pos];
          float d2 = pn + wn[col] - 2.f * accv[i][j][r];
          float d2c = fmaxf(d2, 0.f) + 1e-12f;
          ev = expf(-d2c * inv_s[pos]);
          ev = (ev >= bias) ? ev : 0.f;
        }
        e[r] = ev;
      }
#pragma unroll
      for (int k = 0; k < 2; ++k) {
        int p = i * 8 + q4 * 2 + k;
        if (p < 18) {
          bool top = ((p / 3) & 1) == 0;
          float cc = top ? fmaf(0.729f, e[2 * k], 0.81f * e[2 * k + 1])
                         : fmaf(0.9f, e[2 * k], e[2 * k + 1]);
          psm[(wr * 18 + p) * ESM_P + col] = cc;
        }
      }
    }
  }
  __syncthreads();

  size_t b0s = (size_t)blockIdx.x * 2;
#pragma unroll
  for (int it = 0; it < 5; ++it) {
    int idx = t + 256 * it;
    if (idx >= 1152) break;
    int rowp = idx >> 6;
    int cp = idx & 63;
    int im = rowp / 9, IJ = rowp - im * 9;
    int I = IJ / 3, J = IJ - I * 3;
    const float* basep = &psm[(im * 18 + 6 * I + J) * ESM_P];
    int col0 = 2 * cp, col1 = 2 * cp + 1;
    float v0 = (col0 < 100) ? 0.25f * (basep[col0] + basep[3 * ESM_P + col0]) : 0.f;
    float v1 = (col1 < 100) ? 0.25f * (basep[col1] + basep[3 * ESM_P + col1]) : 0.f;
    u16 h0 = f2bf(v0), h1 = f2bf(v1);
    u16 l0 = f2bf(v0 - bf2f(h0)), l1 = f2bf(v1 - bf2f(h1));
    size_t xrow = b0s * 9 + rowp;
    *(unsigned int*)&Xhi[xrow * 128 + col0] = (unsigned int)h0 | ((unsigned int)h1 << 16);
    *(unsigned int*)&Xlo[xrow * 128 + col0] = (unsigned int)l0 | ((unsigned int)l1 << 16);
    float p = fmaf(v0, v0, v1 * v1);
    for (int off = 32; off; off >>= 1) p += __shfl_down(p, off, 64);
    if ((t & 63) == 0) xn[xrow] = p;
  }
}

// ---------------- 256x256-tile 8-wave split-bf16 MFMA cdist GEMM ----------------
// 512 threads, wave = 64(M) x 128(O) (4x8 frags), 3 MFMAs per frag pair.
// LDS 64 KB: Ah[0..8191] Al[8192..] Bh[16384..] Bl[24576..], slot=(q*256+row)*8.
// dist holds SQUARED distances (+eps).
__global__ __launch_bounds__(512, 2) void gemm_dist_mfma2(
    const u16* __restrict__ Xhi, const u16* __restrict__ Xlo,
    const u16* __restrict__ Whi, const u16* __restrict__ Wlo,
    const float* __restrict__ xn, const float* __restrict__ wn,
    float* __restrict__ dist, int O, int Kp,
    double* __restrict__ acc, int accbase, int c0,
    int sXc, int sWc, int sxnc, int swnc, int sdistc)
{
  __shared__ __align__(16) u16 sm[32768];
  int zi = blockIdx.z, c = c0 + zi;
  Xhi += (size_t)zi * sXc; Xlo += (size_t)zi * sXc;
  Whi += (size_t)c * sWc;  Wlo += (size_t)c * sWc;
  xn += (size_t)zi * sxnc; wn += (size_t)c * swnc;
  dist += (size_t)zi * sdistc;
  acc += (size_t)c * ACC_TOTAL;

  const int t = threadIdx.x;
  const int w = t >> 6, lane = t & 63;
  const int wr = w >> 1, wc = w & 1;        // wr 0..3 (64-row band), wc 0..1 (128-col half)
  const int sq = w & 3, half = w >> 2;      // staging role
  const int m0 = blockIdx.x * 256, o0 = blockIdx.y * 256;
  const int q4 = lane >> 4, r16 = lane & 15;

  f32x4 accv[4][8];
#pragma unroll
  for (int i = 0; i < 4; ++i)
#pragma unroll
    for (int j = 0; j < 8; ++j) accv[i][j] = (f32x4){0.f, 0.f, 0.f, 0.f};

  for (int k0 = 0; k0 < Kp; k0 += 32) {
    const int kk = k0 + sq * 8;
#pragma unroll
    for (int u = 0; u < 2; ++u) {
      const int row = half * 128 + u * 64 + lane;
      const size_t ga = (size_t)(m0 + row) * Kp + kk;
      const size_t gb = (size_t)(o0 + row) * Kp + kk;
      const int ls = (sq * 256 + half * 128 + u * 64) * 8;
      gload16(Xhi + ga, sm + ls);
      gload16(Xlo + ga, sm + 8192 + ls);
      gload16(Whi + gb, sm + 16384 + ls);
      gload16(Wlo + gb, sm + 24576 + ls);
    }
    asm volatile("s_waitcnt vmcnt(0)" ::: "memory");
    __syncthreads();

    bf16x8 Ah[4], Al[4];
#pragma unroll
    for (int i = 0; i < 4; ++i) {
      int ao = (q4 * 256 + wr * 64 + i * 16 + r16) * 8;
      Ah[i] = *(const bf16x8*)(sm + ao);
      Al[i] = *(const bf16x8*)(sm + 8192 + ao);
    }
#pragma unroll
    for (int j = 0; j < 8; ++j) {
      int bo = (q4 * 256 + wc * 128 + j * 16 + r16) * 8;
      bf16x8 Bh = *(const bf16x8*)(sm + 16384 + bo);
      bf16x8 Bl = *(const bf16x8*)(sm + 24576 + bo);
#pragma unroll
      for (int i = 0; i < 4; ++i) {
        accv[i][j] = __builtin_amdgcn_mfma_f32_16x16x32_bf16(Ah[i], Bh, accv[i][j], 0, 0, 0);
        accv[i][j] = __builtin_amdgcn_mfma_f32_16x16x32_bf16(Al[i], Bh, accv[i][j], 0, 0, 0);
        accv[i][j] = __builtin_amdgcn_mfma_f32_16x16x32_bf16(Ah[i], Bl, accv[i][j], 0, 0, 0);
      }
    }
    __syncthreads();
  }

  double s = 0.0, qd = 0.0;
#pragma unroll
  for (int i = 0; i < 4; ++i) {
    const int mb = m0 + wr * 64 + i * 16 + q4 * 4;
    float xnv[4];
#pragma unroll
    for (int r = 0; r < 4; ++r) xnv[r] = xn[mb + r];
#pragma unroll
    for (int j = 0; j < 8; ++j) {
      const int o = o0 + wc * 128 + j * 16 + r16;
      if (o < O) {
        const float wnv = wn[o];
#pragma unroll
        for (int r = 0; r < 4; ++r) {
          float d2 = xnv[r] + wnv - 2.f * accv[i][j][r];
          float d2c = fmaxf(d2, 0.f) + 1e-12f;
          dist[(size_t)(mb + r) * O + o] = d2c;
          s += sqrtf(d2c); qd += (double)d2c;
        }
      }
    }
  }
  for (int off = 32; off; off >>= 1) {
    s += __shfl_down(s, off, 64);
    qd += __shfl_down(qd, off, 64);
  }
  double* redsm = (double*)sm;     // safe: after final K-loop barrier
  if (lane == 0) { redsm[w * 2] = s; redsm[w * 2 + 1] = qd; }
  __syncthreads();
  if (t == 0) {
    s = 0.0; qd = 0.0;
#pragma unroll
    for (int ww = 0; ww < 8; ++ww) { s += redsm[ww * 2]; qd += redsm[ww * 2 + 1]; }
    int stripe = (blockIdx.x + blockIdx.y * gridDim.x) & (STRIPES - 1);
    atomicAdd(&acc[accbase + stripe * 2], s);
    atomicAdd(&acc[accbase + stripe * 2 + 1], qd);
  }
}

// block preamble: reduce 64-stripe acc -> inv = 0.5/var, broadcast via LDS.
__device__ __forceinline__ float block_inv_from_acc(
    const double* __restrict__ acc, int base, double n, float* sh)
{
  __syncthreads();
  int t = threadIdx.x;
  if (t < 64) {
    double s = acc[base + 2 * t], q = acc[base + 2 * t + 1];
    for (int off = 32; off; off >>= 1) {
      s += __shfl_down(s, off, 64);
      q += __shfl_down(q, off, 64);
    }
    if (t == 0) {
      double var = (q - s * s / n) / (n - 1.0);
      *sh = var > 0.0 ? (float)(0.5 / var) : __builtin_inff();
    }
  }
  __syncthreads();
  return *sh;
}

// exp -> crelu(cb1) -> [0.81,0.9,1]/3 pool -> hi/lo (Kp=256) + xn   (dist2 = d^2)
__global__ __launch_bounds__(256) void l2_sfm(
    const float* __restrict__ dist2, const double* __restrict__ acc, double n,
    const float* __restrict__ cb, u16* __restrict__ Xhi, u16* __restrict__ Xlo,
    float* __restrict__ xn, int c0, int sdistc, int sXc, int sxnc)
{
  __shared__ float shinv;
  __shared__ float red[4];
  int zi = blockIdx.z, c = c0 + zi;
  dist2 += (size_t)zi * sdistc;
  Xhi += (size_t)zi * sXc; Xlo += (size_t)zi * sXc; xn += (size_t)zi * sxnc;
  float inv = block_inv_from_acc(acc + (size_t)c * ACC_TOTAL, ACC_L2, n, &shinv);
  int b = blockIdx.x, u = blockIdx.y, ch = threadIdx.x;
  float bias = cb[1];
  float v = 0.f;
  if (ch < 225) {
    const float av[3] = {0.81f, 0.9f, 1.0f};
    float a = 0.f;
#pragma unroll
    for (int vv = 0; vv < 3; ++vv) {
      float d2 = dist2[((size_t)b * 9 + u * 3 + vv) * 225 + ch];
      float e = expf(-d2 * inv);
      e = (e >= bias) ? e : 0.f;
      a = fmaf(e, av[vv], a);
    }
    v = a * (1.f / 3.f);
  }
  size_t row = (size_t)b * 3 + u;
  u16 h = f2bf(v);
  u16 l = f2bf(v - bf2f(h));
  Xhi[row * 256 + ch] = h;
  Xlo[row * 256 + ch] = l;
  float p = v * v;
  for (int off = 32; off; off >>= 1) p += __shfl_down(p, off, 64);
  if ((ch & 63) == 0) red[ch >> 6] = p;
  __syncthreads();
  if (ch == 0) xn[row] = red[0] + red[1] + red[2] + red[3];
}

// exp -> crelu(cb2) -> [0.81,0.9,1]/3 pool -> hi/lo (Kp=640) + xn   (dist3 = d^2)
__global__ __launch_bounds__(256) void l3_sfm(
    const float* __restrict__ dist3, const double* __restrict__ acc, double n,
    const float* __restrict__ cb, u16* __restrict__ Xhi, u16* __restrict__ Xlo,
    float* __restrict__ xn, int c0, int sdistc, int sXc, int sxnc)
{
  __shared__ float shinv;
  __shared__ float red[4];
  int zi = blockIdx.y, c = c0 + zi;
  dist3 += (size_t)zi * sdistc;
  Xhi += (size_t)zi * sXc; Xlo += (size_t)zi * sXc; xn += (size_t)zi * sxnc;
  float inv = block_inv_from_acc(acc + (size_t)c * ACC_TOTAL, ACC_L3, n, &shinv);
  int b = blockIdx.x, t = threadIdx.x;
  float bias = cb[2];
  const float au[3] = {0.81f, 0.9f, 1.0f};
  float p = 0.f;
  for (int ch = t; ch < 640; ch += 256) {
    float v = 0.f;
    if (ch < 625) {
      float a = 0.f;
#pragma unroll
      for (int u = 0; u < 3; ++u) {
        float d2 = dist3[((size_t)b * 3 + u) * 625 + ch];
        float e = expf(-d2 * inv);
        e = (e >= bias) ? e : 0.f;
        a = fmaf(e, au[u], a);
      }
      v = a * (1.f / 3.f);
    }
    u16 h = f2bf(v);
    u16 l = f2bf(v - bf2f(h));
    Xhi[(size_t)b * 640 + ch] = h;
    Xlo[(size_t)b * 640 + ch] = l;
    p = fmaf(v, v, p);
  }
  for (int off = 32; off; off >>= 1) p += __shfl_down(p, off, 64);
  if ((t & 63) == 0) red[t >> 6] = p;
  __syncthreads();
  if (t == 0) xn[b] = red[0] + red[1] + red[2] + red[3];
}

// L4 exp/crelu fused into FC; loops nc channels internally  (dist4 = d^2)
__global__ __launch_bounds__(128) void fc_acc(
    const float* __restrict__ dist4, const double* __restrict__ acc, double n,
    const float* __restrict__ cb, const float* __restrict__ fcw,
    const float* __restrict__ fcb, float* __restrict__ out,
    int c0, int nc, int sdistc)
{
  __shared__ float shinv;
  int b = blockIdx.x, t = threadIdx.x;
  float bias = cb[3];
  float p[10];
#pragma unroll
  for (int k = 0; k < 10; ++k) p[k] = 0.f;
  for (int zi = 0; zi < nc; ++zi) {
    int c = c0 + zi;
    float inv = block_inv_from_acc(acc + (size_t)c * ACC_TOTAL, ACC_L4, n, &shinv);
    const float* d4 = dist4 + (size_t)zi * sdistc;
    for (int j = t; j < 1225; j += 128) {
      float d2 = d4[(size_t)b * 1225 + j];
      float v = expf(-d2 * inv);
      v = (v >= bias) ? v : 0.f;
#pragma unroll
      for (int k = 0; k < 10; ++k) p[k] = fmaf(v, fcw[k * 3675 + c * 1225 + j], p[k]);
    }
  }
#pragma unroll
  for (int k = 0; k < 10; ++k)
    for (int off = 32; off; off >>= 1) p[k] += __shfl_down(p[k], off, 64);
  __shared__ float red[2][10];
  int wave = t >> 6;
  if ((t & 63) == 0) {
#pragma unroll
    for (int k = 0; k < 10; ++k) red[wave][k] = p[k];
  }
  __syncthreads();
  if (t < 10) {
    float v = red[0][t] + red[1][t];
    if (c0 == 0) out[(size_t)b * 10 + t] = fcb[t] + v;
    else         out[(size_t)b * 10 + t] += v;
  }
}

extern "C" void kernel_launch(void* const* d_in, const int* in_sizes, int n_in,
                              void* d_out, int out_size, void* d_ws, size_t ws_size,
                              hipStream_t stream) {
  const float* x   = (const float*)d_in[0];
  const float* w1  = (const float*)d_in[1];
  const float* w2  = (const float*)d_in[2];
  const float* w3  = (const float*)d_in[3];
  const float* w4  = (const float*)d_in[4];
  const float* fcw = (const float*)d_in[5];
  const float* fcb = (const float*)d_in[6];
  const float* cb  = (const float*)d_in[7];
  float* out = (float*)d_out;
  const int B = in_sizes[0] / (3 * 28 * 28);   // 4096
  const int M2 = B * 9, M3 = B * 3;
  const int NB = B / 2;

  // padded weight sizes per channel (Opad x Kp): L2 256x128, L3 768x256, L4 1280x640
  const size_t W2SZ = 256 * 128, W3SZ = 768 * 256, W4SZ = (size_t)1280 * 640;
  const size_t WTOT = 3 * (W2SZ + W3SZ + W4SZ);

  bool batched = true;
  u16 *Xbase, *Whi, *Wlo, *W1h, *W1l;
  float *wn, *w1n, *xn, *inv36, *part;
  double* accd;
  float* Sf;
  for (int attempt = 0; attempt < 2; ++attempt) {
    size_t cur = 0;
    char* basep = (char*)d_ws;
    auto take = [&](size_t bytes) {
      void* r = basep + cur;
      cur = (cur + bytes + 255) & ~(size_t)255;
      return r;
    };
    int nc = batched ? 3 : 1;
    size_t Ssz = (size_t)M2 * 225 * 4 * nc;            // largest dist buffer
    Sf = (float*)take(Ssz);
    Xbase = (u16*)take((size_t)M2 * 128 * 2 * 2 * nc);
    Whi = (u16*)take(WTOT * 2); Wlo = (u16*)take(WTOT * 2);
    W1h = (u16*)take(12288 * 2); W1l = (u16*)take(12288 * 2);
    wn  = (float*)take(3 * (256 + 768 + 1280) * 4);
    w1n = (float*)take(384 * 4);
    xn    = (float*)take((size_t)M2 * 4 * nc);
    inv36 = (float*)take(40 * 4 * nc);
    part  = (float*)take((size_t)72 * NB * 4 * nc);
    accd  = (double*)take(3 * ACC_TOTAL * 8);
    if (cur <= ws_size) break;
    batched = false;
  }
  const int nc = batched ? 3 : 1;

  const int sPartc = batched ? 72 * NB : 0;
  const int sInvc  = batched ? 40 : 0;
  const int sX2c   = batched ? M2 * 128 * 2 : 0;
  const int sX3c   = batched ? M3 * 256 * 2 : 0;
  const int sX4c   = batched ? B * 640 * 2 : 0;
  const int sD2c   = batched ? M2 * 225 : 0;
  const int sD3c   = batched ? M3 * 625 : 0;
  const int sD4c   = batched ? B * 1225 : 0;
  const int sXn2c  = batched ? M2 : 0;
  const int sXn3c  = batched ? M3 : 0;
  const int sXn4c  = batched ? B : 0;

  u16* x2hi = Xbase;   u16* x2lo = Xbase + (size_t)M2 * 128;
  u16* x3hi = Xbase;   u16* x3lo = Xbase + (size_t)M3 * 256;
  u16* x4hi = Xbase;   u16* x4lo = Xbase + (size_t)B * 640;
  u16* Whi2 = Whi;                 u16* Wlo2 = Wlo;                 float* wn2 = wn;
  u16* Whi3 = Whi + 3 * W2SZ;      u16* Wlo3 = Wlo + 3 * W2SZ;      float* wn3 = wn + 3 * 256;
  u16* Whi4 = Whi + 3 * (W2SZ + W3SZ); u16* Wlo4 = Wlo + 3 * (W2SZ + W3SZ);
  float* wn4 = wn + 3 * (256 + 768);

  zero_acc_kernel<<<(3 * ACC_TOTAL + 255) / 256, 256, 0, stream>>>(accd, 3 * ACC_TOTAL);
  w_prep<<<dim3(128, 3),  128, 0, stream>>>(w1, 100, 25,  128, 32,  W1h,  W1l,  w1n);
  w_prep<<<dim3(256, 3),  128, 0, stream>>>(w2, 225, 100, 256, 128, Whi2, Wlo2, wn2);
  w_prep<<<dim3(768, 3),  128, 0, stream>>>(w3, 625, 225, 768, 256, Whi3, Wlo3, wn3);
  w_prep<<<dim3(1280, 3), 128, 0, stream>>>(w4, 1225, 625, 1280, 640, Whi4, Wlo4, wn4);

  for (int c0 = 0; c0 < 3; c0 += nc) {
    // L1 (MFMA two-pass, extraction fused)
    l1_gemm_reduce<<<dim3(NB, nc), 256, 0, stream>>>(
        x, W1h, W1l, w1n, part, NB, c0, sPartc);
    l1_part_fin<<<dim3(36, nc), 256, 0, stream>>>(part, NB, inv36, (double)B * 100.0,
                                                  sPartc, sInvc);
    l1_gemm_sfm<<<dim3(NB, nc), 256, 0, stream>>>(
        x, W1h, W1l, w1n, inv36, cb, x2hi, x2lo, xn, c0, sInvc, sX2c, sXn2c);

    // L2: (M2 x 128) x (256 x 128) -> dist2 (M2 x 225)
    gemm_dist_mfma2<<<dim3(M2 / 256, 1, nc), 512, 0, stream>>>(
        x2hi, x2lo, Whi2, Wlo2, xn, wn2, Sf, 225, 128, accd, ACC_L2, c0,
        sX2c, (int)W2SZ, sXn2c, 256, sD2c);
    l2_sfm<<<dim3(B, 3, nc), 256, 0, stream>>>(
        Sf, accd, (double)M2 * 225.0, cb, x3hi, x3lo, xn, c0, sD2c, sX3c, sXn3c);

    // L3: (M3 x 256) x (768 x 256) -> dist3 (M3 x 625)
    gemm_dist_mfma2<<<dim3(M3 / 256, 3, nc), 512, 0, stream>>>(
        x3hi, x3lo, Whi3, Wlo3, xn, wn3, Sf, 625, 256, accd, ACC_L3, c0,
        sX3c, (int)W3SZ, sXn3c, 768, sD3c);
    l3_sfm<<<dim3(B, nc), 256, 0, stream>>>(
        Sf, accd, (double)M3 * 625.0, cb, x4hi, x4lo, xn, c0, sD3c, sX4c, sXn4c);

    // L4: (B x 640) x (1280 x 640) -> dist4 (B x 1225)
    gemm_dist_mfma2<<<dim3(B / 256, 5, nc), 512, 0, stream>>>(
        x4hi, x4lo, Whi4, Wlo4, xn, wn4, Sf, 1225, 640, accd, ACC_L4, c0,
        sX4c, (int)W4SZ, sXn4c, 1280, sD4c);
    fc_acc<<<B, 128, 0, stream>>>(
        Sf, accd, (double)B * 1225.0, cb, fcw, fcb, out, c0, nc, sD4c);
  }
}

// Round 7
// 594.308 us; speedup vs baseline: 1.0899x; 1.0899x over previous
//
#include <hip/hip_runtime.h>

// SOMNetwork forward. All four rbf/cdist layers via split-bf16 MFMA GEMM
// (hi/lo decomposition, 3 MFMAs/product). L1: patch extraction fused into the
// GEMM blocks, two-pass (std reduce, then fused exp/crelu/2x2-pool epilogue).
// L2/L3/L4: 256x256-tile 8-wave GEMM, dist buffer holds squared distances.
// Channels batched into grid z. Round 7: native v_exp_f32 / v_sqrt_f32
// (library expf/sqrtf were ~20-inst and dominated VALU in the sfm kernels).

typedef unsigned short u16;
typedef short bf16x8 __attribute__((ext_vector_type(8)));
typedef float f32x4 __attribute__((ext_vector_type(4)));

#define STRIPES 64
#define ACC_L2 0            // 64 stripes * 2 doubles per layer region
#define ACC_L3 128
#define ACC_L4 256
#define ACC_TOTAL 384
#define ESM_P 132

__device__ __forceinline__ u16 f2bf(float f) {
  unsigned int u = __float_as_uint(f);
  unsigned int r = (u + 0x7fffu + ((u >> 16) & 1u)) >> 16;
  return (u16)r;
}
__device__ __forceinline__ float bf2f(u16 h) {
  return __uint_as_float(((unsigned int)h) << 16);
}
__device__ __forceinline__ float fexp(float x) { return __expf(x); }            // v_exp_f32
__device__ __forceinline__ float fsqrt(float x) { return __builtin_amdgcn_sqrtf(x); } // v_sqrt_f32
__device__ __forceinline__ void gload16(const void* g, const void* l) {
  __builtin_amdgcn_global_load_lds(
      (const __attribute__((address_space(1))) unsigned int*)g,
      (__attribute__((address_space(3))) unsigned int*)l, 16, 0, 0);
}

__global__ void zero_acc_kernel(double* __restrict__ acc, int n) {
  int i = blockIdx.x * blockDim.x + threadIdx.x;
  if (i < n) acc[i] = 0.0;
}

// ---------------- weight prep: fp32 -> hi/lo bf16 (padded) + row norms ----------------
__global__ __launch_bounds__(128) void w_prep(
    const float* __restrict__ W, int O, int K, int Opad, int Kp,
    u16* __restrict__ hi, u16* __restrict__ lo, float* __restrict__ wn)
{
  __shared__ float red[2];
  int o = blockIdx.x, cc = blockIdx.y, t = threadIdx.x;
  const float* src = W + ((size_t)cc * O + o) * K;
  u16* dh = hi + ((size_t)cc * Opad + o) * Kp;
  u16* dl = lo + ((size_t)cc * Opad + o) * Kp;
  float p = 0.f;
  for (int k = t; k < Kp; k += 128) {
    float v = (o < O && k < K) ? src[k] : 0.f;
    u16 h = f2bf(v);
    u16 l = f2bf(v - bf2f(h));
    dh[k] = h; dl[k] = l;
    p = fmaf(v, v, p);
  }
  for (int off = 32; off; off >>= 1) p += __shfl_down(p, off, 64);
  if ((t & 63) == 0) red[t >> 6] = p;
  __syncthreads();
  if (t == 0) wn[(size_t)cc * Opad + o] = red[0] + red[1];
}

// ---------------- L1 shared mainloop: fused patch extraction + MFMA ----------------
__device__ __forceinline__ void l1_mainloop(
    const float* __restrict__ x, int b0, int c,
    const u16* __restrict__ Wh, const u16* __restrict__ Wl,
    u16* sm, float* img, float* pnsm, float* pnloc, f32x4 (&accv)[4][4])
{
  const int t = threadIdx.x;
  const int w = t >> 6, lane = t & 63;
  {
    const int kk = (w & 3) * 8;
#pragma unroll
    for (int u = 0; u < 2; ++u) {
      const size_t gb = (size_t)(u * 64 + lane) * 32 + kk;
      const int ls = ((w & 3) * 128 + u * 64) * 8;
      gload16(Wh + gb, sm + 8192 + ls);
      gload16(Wl + gb, sm + 12288 + ls);
    }
  }
#pragma unroll
  for (int im = 0; im < 2; ++im) {
    if (t < 196)
      ((float4*)(img + im * 784))[t] =
          ((const float4*)(x + ((size_t)(b0 + im) * 3 + c) * 784))[t];
  }
  __syncthreads();
  for (int s = t; s < 512; s += 256) {
    int q = s >> 7, row = s & 127;
    int im = row >> 6, pr = row & 63;
    int pi = pr / 6, pj = pr - pi * 6;
    const float* ib = img + im * 784 + pi * 4 * 28 + pj * 4;
    float v[8]; float pn = 0.f;
#pragma unroll
    for (int e = 0; e < 8; ++e) {
      int k = q * 8 + e;
      float val = 0.f;
      if (pr < 36 && k < 25) { int r = k / 5, ss = k - r * 5; val = ib[r * 28 + ss]; }
      v[e] = val; pn = fmaf(val, val, pn);
    }
    u16 hi8[8], lo8[8];
#pragma unroll
    for (int e = 0; e < 8; ++e) {
      u16 h = f2bf(v[e]); hi8[e] = h; lo8[e] = f2bf(v[e] - bf2f(h));
    }
    *(bf16x8*)(sm + (q * 128 + row) * 8) = *(bf16x8*)hi8;
    *(bf16x8*)(sm + 4096 + (q * 128 + row) * 8) = *(bf16x8*)lo8;
    pnsm[s] = pn;
  }
  asm volatile("s_waitcnt vmcnt(0)" ::: "memory");
  __syncthreads();
  if (t < 128) pnloc[t] = pnsm[t] + pnsm[128 + t] + pnsm[256 + t] + pnsm[384 + t];

  const int wr = w >> 1, wc = w & 1;
  const int q4 = lane >> 4, r16 = lane & 15;
  bf16x8 Ah[4], Al[4], Bh[4], Bl[4];
#pragma unroll
  for (int i = 0; i < 4; ++i) {
    int ao = (q4 * 128 + wr * 64 + i * 16 + r16) * 8;
    int bo = (q4 * 128 + wc * 64 + i * 16 + r16) * 8;
    Ah[i] = *(const bf16x8*)(sm + ao);
    Al[i] = *(const bf16x8*)(sm + 4096 + ao);
    Bh[i] = *(const bf16x8*)(sm + 8192 + bo);
    Bl[i] = *(const bf16x8*)(sm + 12288 + bo);
  }
#pragma unroll
  for (int i = 0; i < 4; ++i)
#pragma unroll
    for (int j = 0; j < 4; ++j) {
      accv[i][j] = __builtin_amdgcn_mfma_f32_16x16x32_bf16(Ah[i], Bh[j], accv[i][j], 0, 0, 0);
      accv[i][j] = __builtin_amdgcn_mfma_f32_16x16x32_bf16(Al[i], Bh[j], accv[i][j], 0, 0, 0);
      accv[i][j] = __builtin_amdgcn_mfma_f32_16x16x32_bf16(Ah[i], Bl[j], accv[i][j], 0, 0, 0);
    }
  __syncthreads();   // pnloc visible to epilogue
}

// ---------------- L1 pass A: per-position s/q -> per-block float partials ----------------
__global__ __launch_bounds__(256) void l1_gemm_reduce(
    const float* __restrict__ x, const u16* __restrict__ W1h, const u16* __restrict__ W1l,
    const float* __restrict__ w1n, float* __restrict__ part, int NB, int c0, int sPartc)
{
  __shared__ __align__(16) u16 sm[16384];
  __shared__ float img[1568];
  __shared__ float pnsm[512];
  __shared__ float pnloc[128];
  __shared__ float sq[72];
  int t = threadIdx.x, zi = blockIdx.y, c = c0 + zi;
  const u16* Wh = W1h + (size_t)c * 4096;
  const u16* Wl = W1l + (size_t)c * 4096;
  const float* wn = w1n + (size_t)c * 128;
  part += (size_t)zi * sPartc;
  if (t < 72) sq[t] = 0.f;
  f32x4 accv[4][4];
#pragma unroll
  for (int i = 0; i < 4; ++i)
#pragma unroll
    for (int j = 0; j < 4; ++j) accv[i][j] = (f32x4){0.f, 0.f, 0.f, 0.f};
  const int b0 = blockIdx.x * 2;
  l1_mainloop(x, b0, c, Wh, Wl, sm, img, pnsm, pnloc, accv);

  const int w = t >> 6, lane = t & 63;
  const int wr = w >> 1, wc = w & 1, q4 = lane >> 4, r16 = lane & 15;
#pragma unroll
  for (int i = 0; i < 4; ++i) {
#pragma unroll
    for (int r = 0; r < 4; ++r) {
      int pos = i * 16 + q4 * 4 + r;
      if (pos < 36) {
        float pn = pnloc[wr * 64 + pos];
        float s = 0.f, q = 0.f;
#pragma unroll
        for (int j = 0; j < 4; ++j) {
          int col = wc * 64 + j * 16 + r16;
          if (col < 100) {
            float d2 = pn + wn[col] - 2.f * accv[i][j][r];
            float d2c = fmaxf(d2, 0.f) + 1e-12f;
            s += fsqrt(d2c);
            q += d2c;
          }
        }
        s += __shfl_down(s, 8, 16);
        s += __shfl_down(s, 4, 16);
        s += __shfl_down(s, 2, 16);
        s += __shfl_down(s, 1, 16);
        q += __shfl_down(q, 8, 16);
        q += __shfl_down(q, 4, 16);
        q += __shfl_down(q, 2, 16);
        q += __shfl_down(q, 1, 16);
        if (r16 == 0) {
          atomicAdd(&sq[pos], s);
          atomicAdd(&sq[36 + pos], q);
        }
      }
    }
  }
  __syncthreads();
  if (t < 72) part[(size_t)t * NB + blockIdx.x] = sq[t];
}

__global__ __launch_bounds__(256) void l1_part_fin(
    const float* __restrict__ part, int NB, float* __restrict__ inv36, double n,
    int sPartc, int sInvc)
{
  __shared__ double sh[8];
  int pos = blockIdx.x, zi = blockIdx.y, t = threadIdx.x;
  part += (size_t)zi * sPartc; inv36 += (size_t)zi * sInvc;
  double s = 0.0, q = 0.0;
  for (int b = t; b < NB; b += 256) {
    s += part[(size_t)pos * NB + b];
    q += part[(size_t)(36 + pos) * NB + b];
  }
  for (int off = 32; off; off >>= 1) {
    s += __shfl_down(s, off, 64);
    q += __shfl_down(q, off, 64);
  }
  if ((t & 63) == 0) { sh[(t >> 6) * 2] = s; sh[(t >> 6) * 2 + 1] = q; }
  __syncthreads();
  if (t == 0) {
    s = sh[0] + sh[2] + sh[4] + sh[6];
    q = sh[1] + sh[3] + sh[5] + sh[7];
    double var = (q - s * s / n) / (n - 1.0);
    inv36[pos] = var > 0.0 ? (float)(0.5 / var) : __builtin_inff();
  }
}

// ---------------- L1 pass B: fused exp/crelu/2x2-alpha-pool epilogue ----------------
__global__ __launch_bounds__(256) void l1_gemm_sfm(
    const float* __restrict__ x, const u16* __restrict__ W1h, const u16* __restrict__ W1l,
    const float* __restrict__ w1n, const float* __restrict__ inv36,
    const float* __restrict__ cb,
    u16* __restrict__ Xhi, u16* __restrict__ Xlo, float* __restrict__ xn,
    int c0, int sInvc, int sXc, int sxnc)
{
  __shared__ __align__(16) u16 sm[16384];
  __shared__ float img[1568];
  __shared__ float pnsm[512];
  __shared__ float pnloc[128];
  __shared__ float psm[2 * 18 * ESM_P];
  __shared__ float inv_s[36];
  int t = threadIdx.x, zi = blockIdx.y, c = c0 + zi;
  const u16* Wh = W1h + (size_t)c * 4096;
  const u16* Wl = W1l + (size_t)c * 4096;
  const float* wn = w1n + (size_t)c * 128;
  inv36 += (size_t)zi * sInvc;
  Xhi += (size_t)zi * sXc; Xlo += (size_t)zi * sXc; xn += (size_t)zi * sxnc;
  if (t < 36) inv_s[t] = inv36[t];
  f32x4 accv[4][4];
#pragma unroll
  for (int i = 0; i < 4; ++i)
#pragma unroll
    for (int j = 0; j < 4; ++j) accv[i][j] = (f32x4){0.f, 0.f, 0.f, 0.f};
  const int b0 = blockIdx.x * 2;
  l1_mainloop(x, b0, c, Wh, Wl, sm, img, pnsm, pnloc, accv);

  const float bias = cb[0];
  const int w = t >> 6, lane = t & 63;
  const int wr = w >> 1, wc = w & 1, q4 = lane >> 4, r16 = lane & 15;
#pragma unroll
  for (int i = 0; i < 4; ++i) {
#pragma unroll
    for (int j = 0; j < 4; ++j) {
      int col = wc * 64 + j * 16 + r16;
      float e[4];
#pragma unroll
      for (int r = 0; r < 4; ++r) {
        int pos = i * 16 + q4 * 4 + r;
        float ev = 0.f;
        if (pos < 36) {
          float pn = pnloc[wr * 64 + pos];
          float d2 = pn + wn[col] - 2.f * accv[i][j][r];
          float d2c = fmaxf(d2, 0.f) + 1e-12f;
          ev = fexp(-d2c * inv_s[pos]);
          ev = (ev >= bias) ? ev : 0.f;
        }
        e[r] = ev;
      }
#pragma unroll
      for (int k = 0; k < 2; ++k) {
        int p = i * 8 + q4 * 2 + k;
        if (p < 18) {
          bool top = ((p / 3) & 1) == 0;
          float cc = top ? fmaf(0.729f, e[2 * k], 0.81f * e[2 * k + 1])
                         : fmaf(0.9f, e[2 * k], e[2 * k + 1]);
          psm[(wr * 18 + p) * ESM_P + col] = cc;
        }
      }
    }
  }
  __syncthreads();

  size_t b0s = (size_t)blockIdx.x * 2;
#pragma unroll
  for (int it = 0; it < 5; ++it) {
    int idx = t + 256 * it;
    if (idx >= 1152) break;
    int rowp = idx >> 6;
    int cp = idx & 63;
    int im = rowp / 9, IJ = rowp - im * 9;
    int I = IJ / 3, J = IJ - I * 3;
    const float* basep = &psm[(im * 18 + 6 * I + J) * ESM_P];
    int col0 = 2 * cp, col1 = 2 * cp + 1;
    float v0 = (col0 < 100) ? 0.25f * (basep[col0] + basep[3 * ESM_P + col0]) : 0.f;
    float v1 = (col1 < 100) ? 0.25f * (basep[col1] + basep[3 * ESM_P + col1]) : 0.f;
    u16 h0 = f2bf(v0), h1 = f2bf(v1);
    u16 l0 = f2bf(v0 - bf2f(h0)), l1 = f2bf(v1 - bf2f(h1));
    size_t xrow = b0s * 9 + rowp;
    *(unsigned int*)&Xhi[xrow * 128 + col0] = (unsigned int)h0 | ((unsigned int)h1 << 16);
    *(unsigned int*)&Xlo[xrow * 128 + col0] = (unsigned int)l0 | ((unsigned int)l1 << 16);
    float p = fmaf(v0, v0, v1 * v1);
    for (int off = 32; off; off >>= 1) p += __shfl_down(p, off, 64);
    if ((t & 63) == 0) xn[xrow] = p;
  }
}

// ---------------- 256x256-tile 8-wave split-bf16 MFMA cdist GEMM ----------------
__global__ __launch_bounds__(512, 2) void gemm_dist_mfma2(
    const u16* __restrict__ Xhi, const u16* __restrict__ Xlo,
    const u16* __restrict__ Whi, const u16* __restrict__ Wlo,
    const float* __restrict__ xn, const float* __restrict__ wn,
    float* __restrict__ dist, int O, int Kp,
    double* __restrict__ acc, int accbase, int c0,
    int sXc, int sWc, int sxnc, int swnc, int sdistc)
{
  __shared__ __align__(16) u16 sm[32768];
  int zi = blockIdx.z, c = c0 + zi;
  Xhi += (size_t)zi * sXc; Xlo += (size_t)zi * sXc;
  Whi += (size_t)c * sWc;  Wlo += (size_t)c * sWc;
  xn += (size_t)zi * sxnc; wn += (size_t)c * swnc;
  dist += (size_t)zi * sdistc;
  acc += (size_t)c * ACC_TOTAL;

  const int t = threadIdx.x;
  const int w = t >> 6, lane = t & 63;
  const int wr = w >> 1, wc = w & 1;
  const int sq = w & 3, half = w >> 2;
  const int m0 = blockIdx.x * 256, o0 = blockIdx.y * 256;
  const int q4 = lane >> 4, r16 = lane & 15;

  f32x4 accv[4][8];
#pragma unroll
  for (int i = 0; i < 4; ++i)
#pragma unroll
    for (int j = 0; j < 8; ++j) accv[i][j] = (f32x4){0.f, 0.f, 0.f, 0.f};

  for (int k0 = 0; k0 < Kp; k0 += 32) {
    const int kk = k0 + sq * 8;
#pragma unroll
    for (int u = 0; u < 2; ++u) {
      const int row = half * 128 + u * 64 + lane;
      const size_t ga = (size_t)(m0 + row) * Kp + kk;
      const size_t gb = (size_t)(o0 + row) * Kp + kk;
      const int ls = (sq * 256 + half * 128 + u * 64) * 8;
      gload16(Xhi + ga, sm + ls);
      gload16(Xlo + ga, sm + 8192 + ls);
      gload16(Whi + gb, sm + 16384 + ls);
      gload16(Wlo + gb, sm + 24576 + ls);
    }
    asm volatile("s_waitcnt vmcnt(0)" ::: "memory");
    __syncthreads();

    bf16x8 Ah[4], Al[4];
#pragma unroll
    for (int i = 0; i < 4; ++i) {
      int ao = (q4 * 256 + wr * 64 + i * 16 + r16) * 8;
      Ah[i] = *(const bf16x8*)(sm + ao);
      Al[i] = *(const bf16x8*)(sm + 8192 + ao);
    }
#pragma unroll
    for (int j = 0; j < 8; ++j) {
      int bo = (q4 * 256 + wc * 128 + j * 16 + r16) * 8;
      bf16x8 Bh = *(const bf16x8*)(sm + 16384 + bo);
      bf16x8 Bl = *(const bf16x8*)(sm + 24576 + bo);
#pragma unroll
      for (int i = 0; i < 4; ++i) {
        accv[i][j] = __builtin_amdgcn_mfma_f32_16x16x32_bf16(Ah[i], Bh, accv[i][j], 0, 0, 0);
        accv[i][j] = __builtin_amdgcn_mfma_f32_16x16x32_bf16(Al[i], Bh, accv[i][j], 0, 0, 0);
        accv[i][j] = __builtin_amdgcn_mfma_f32_16x16x32_bf16(Ah[i], Bl, accv[i][j], 0, 0, 0);
      }
    }
    __syncthreads();
  }

  double s = 0.0, qd = 0.0;
#pragma unroll
  for (int i = 0; i < 4; ++i) {
    const int mb = m0 + wr * 64 + i * 16 + q4 * 4;
    float xnv[4];
#pragma unroll
    for (int r = 0; r < 4; ++r) xnv[r] = xn[mb + r];
    float sf = 0.f, qf = 0.f;       // fp32 partials over 32 values, then promote
#pragma unroll
    for (int j = 0; j < 8; ++j) {
      const int o = o0 + wc * 128 + j * 16 + r16;
      if (o < O) {
        const float wnv = wn[o];
#pragma unroll
        for (int r = 0; r < 4; ++r) {
          float d2 = xnv[r] + wnv - 2.f * accv[i][j][r];
          float d2c = fmaxf(d2, 0.f) + 1e-12f;
          dist[(size_t)(mb + r) * O + o] = d2c;
          sf += fsqrt(d2c); qf += d2c;
        }
      }
    }
    s += sf; qd += qf;
  }
  for (int off = 32; off; off >>= 1) {
    s += __shfl_down(s, off, 64);
    qd += __shfl_down(qd, off, 64);
  }
  double* redsm = (double*)sm;     // safe: after final K-loop barrier
  if (lane == 0) { redsm[w * 2] = s; redsm[w * 2 + 1] = qd; }
  __syncthreads();
  if (t == 0) {
    s = 0.0; qd = 0.0;
#pragma unroll
    for (int ww = 0; ww < 8; ++ww) { s += redsm[ww * 2]; qd += redsm[ww * 2 + 1]; }
    int stripe = (blockIdx.x + blockIdx.y * gridDim.x) & (STRIPES - 1);
    atomicAdd(&acc[accbase + stripe * 2], s);
    atomicAdd(&acc[accbase + stripe * 2 + 1], qd);
  }
}

// block preamble: reduce 64-stripe acc -> inv = 0.5/var, broadcast via LDS.
__device__ __forceinline__ float block_inv_from_acc(
    const double* __restrict__ acc, int base, double n, float* sh)
{
  __syncthreads();
  int t = threadIdx.x;
  if (t < 64) {
    double s = acc[base + 2 * t], q = acc[base + 2 * t + 1];
    for (int off = 32; off; off >>= 1) {
      s += __shfl_down(s, off, 64);
      q += __shfl_down(q, off, 64);
    }
    if (t == 0) {
      double var = (q - s * s / n) / (n - 1.0);
      *sh = var > 0.0 ? (float)(0.5 / var) : __builtin_inff();
    }
  }
  __syncthreads();
  return *sh;
}

// exp -> crelu(cb1) -> [0.81,0.9,1]/3 pool -> hi/lo (Kp=256) + xn   (dist2 = d^2)
__global__ __launch_bounds__(256) void l2_sfm(
    const float* __restrict__ dist2, const double* __restrict__ acc, double n,
    const float* __restrict__ cb, u16* __restrict__ Xhi, u16* __restrict__ Xlo,
    float* __restrict__ xn, int c0, int sdistc, int sXc, int sxnc)
{
  __shared__ float shinv;
  __shared__ float red[4];
  int zi = blockIdx.z, c = c0 + zi;
  dist2 += (size_t)zi * sdistc;
  Xhi += (size_t)zi * sXc; Xlo += (size_t)zi * sXc; xn += (size_t)zi * sxnc;
  float inv = block_inv_from_acc(acc + (size_t)c * ACC_TOTAL, ACC_L2, n, &shinv);
  int b = blockIdx.x, u = blockIdx.y, ch = threadIdx.x;
  float bias = cb[1];
  float v = 0.f;
  if (ch < 225) {
    const float av[3] = {0.81f, 0.9f, 1.0f};
    float a = 0.f;
#pragma unroll
    for (int vv = 0; vv < 3; ++vv) {
      float d2 = dist2[((size_t)b * 9 + u * 3 + vv) * 225 + ch];
      float e = fexp(-d2 * inv);
      e = (e >= bias) ? e : 0.f;
      a = fmaf(e, av[vv], a);
    }
    v = a * (1.f / 3.f);
  }
  size_t row = (size_t)b * 3 + u;
  u16 h = f2bf(v);
  u16 l = f2bf(v - bf2f(h));
  Xhi[row * 256 + ch] = h;
  Xlo[row * 256 + ch] = l;
  float p = v * v;
  for (int off = 32; off; off >>= 1) p += __shfl_down(p, off, 64);
  if ((ch & 63) == 0) red[ch >> 6] = p;
  __syncthreads();
  if (ch == 0) xn[row] = red[0] + red[1] + red[2] + red[3];
}

// exp -> crelu(cb2) -> [0.81,0.9,1]/3 pool -> hi/lo (Kp=640) + xn   (dist3 = d^2)
__global__ __launch_bounds__(256) void l3_sfm(
    const float* __restrict__ dist3, const double* __restrict__ acc, double n,
    const float* __restrict__ cb, u16* __restrict__ Xhi, u16* __restrict__ Xlo,
    float* __restrict__ xn, int c0, int sdistc, int sXc, int sxnc)
{
  __shared__ float shinv;
  __shared__ float red[4];
  int zi = blockIdx.y, c = c0 + zi;
  dist3 += (size_t)zi * sdistc;
  Xhi += (size_t)zi * sXc; Xlo += (size_t)zi * sXc; xn += (size_t)zi * sxnc;
  float inv = block_inv_from_acc(acc + (size_t)c * ACC_TOTAL, ACC_L3, n, &shinv);
  int b = blockIdx.x, t = threadIdx.x;
  float bias = cb[2];
  const float au[3] = {0.81f, 0.9f, 1.0f};
  float p = 0.f;
  for (int ch = t; ch < 640; ch += 256) {
    float v = 0.f;
    if (ch < 625) {
      float a = 0.f;
#pragma unroll
      for (int u = 0; u < 3; ++u) {
        float d2 = dist3[((size_t)b * 3 + u) * 625 + ch];
        float e = fexp(-d2 * inv);
        e = (e >= bias) ? e : 0.f;
        a = fmaf(e, au[u], a);
      }
      v = a * (1.f / 3.f);
    }
    u16 h = f2bf(v);
    u16 l = f2bf(v - bf2f(h));
    Xhi[(size_t)b * 640 + ch] = h;
    Xlo[(size_t)b * 640 + ch] = l;
    p = fmaf(v, v, p);
  }
  for (int off = 32; off; off >>= 1) p += __shfl_down(p, off, 64);
  if ((t & 63) == 0) red[t >> 6] = p;
  __syncthreads();
  if (t == 0) xn[b] = red[0] + red[1] + red[2] + red[3];
}

// L4 exp/crelu fused into FC; loops nc channels internally  (dist4 = d^2)
__global__ __launch_bounds__(128) void fc_acc(
    const float* __restrict__ dist4, const double* __restrict__ acc, double n,
    const float* __restrict__ cb, const float* __restrict__ fcw,
    const float* __restrict__ fcb, float* __restrict__ out,
    int c0, int nc, int sdistc)
{
  __shared__ float shinv;
  int b = blockIdx.x, t = threadIdx.x;
  float bias = cb[3];
  float p[10];
#pragma unroll
  for (int k = 0; k < 10; ++k) p[k] = 0.f;
  for (int zi = 0; zi < nc; ++zi) {
    int c = c0 + zi;
    float inv = block_inv_from_acc(acc + (size_t)c * ACC_TOTAL, ACC_L4, n, &shinv);
    const float* d4 = dist4 + (size_t)zi * sdistc;
    for (int j = t; j < 1225; j += 128) {
      float d2 = d4[(size_t)b * 1225 + j];
      float v = fexp(-d2 * inv);
      v = (v >= bias) ? v : 0.f;
#pragma unroll
      for (int k = 0; k < 10; ++k) p[k] = fmaf(v, fcw[k * 3675 + c * 1225 + j], p[k]);
    }
  }
#pragma unroll
  for (int k = 0; k < 10; ++k)
    for (int off = 32; off; off >>= 1) p[k] += __shfl_down(p[k], off, 64);
  __shared__ float red[2][10];
  int wave = t >> 6;
  if ((t & 63) == 0) {
#pragma unroll
    for (int k = 0; k < 10; ++k) red[wave][k] = p[k];
  }
  __syncthreads();
  if (t < 10) {
    float v = red[0][t] + red[1][t];
    if (c0 == 0) out[(size_t)b * 10 + t] = fcb[t] + v;
    else         out[(size_t)b * 10 + t] += v;
  }
}

extern "C" void kernel_launch(void* const* d_in, const int* in_sizes, int n_in,
                              void* d_out, int out_size, void* d_ws, size_t ws_size,
                              hipStream_t stream) {
  const float* x   = (const float*)d_in[0];
  const float* w1  = (const float*)d_in[1];
  const float* w2  = (const float*)d_in[2];
  const float* w3  = (const float*)d_in[3];
  const float* w4  = (const float*)d_in[4];
  const float* fcw = (const float*)d_in[5];
  const float* fcb = (const float*)d_in[6];
  const float* cb  = (const float*)d_in[7];
  float* out = (float*)d_out;
  const int B = in_sizes[0] / (3 * 28 * 28);   // 4096
  const int M2 = B * 9, M3 = B * 3;
  const int NB = B / 2;

  const size_t W2SZ = 256 * 128, W3SZ = 768 * 256, W4SZ = (size_t)1280 * 640;
  const size_t WTOT = 3 * (W2SZ + W3SZ + W4SZ);

  bool batched = true;
  u16 *Xbase, *Whi, *Wlo, *W1h, *W1l;
  float *wn, *w1n, *xn, *inv36, *part;
  double* accd;
  float* Sf;
  for (int attempt = 0; attempt < 2; ++attempt) {
    size_t cur = 0;
    char* basep = (char*)d_ws;
    auto take = [&](size_t bytes) {
      void* r = basep + cur;
      cur = (cur + bytes + 255) & ~(size_t)255;
      return r;
    };
    int nc = batched ? 3 : 1;
    size_t Ssz = (size_t)M2 * 225 * 4 * nc;
    Sf = (float*)take(Ssz);
    Xbase = (u16*)take((size_t)M2 * 128 * 2 * 2 * nc);
    Whi = (u16*)take(WTOT * 2); Wlo = (u16*)take(WTOT * 2);
    W1h = (u16*)take(12288 * 2); W1l = (u16*)take(12288 * 2);
    wn  = (float*)take(3 * (256 + 768 + 1280) * 4);
    w1n = (float*)take(384 * 4);
    xn    = (float*)take((size_t)M2 * 4 * nc);
    inv36 = (float*)take(40 * 4 * nc);
    part  = (float*)take((size_t)72 * NB * 4 * nc);
    accd  = (double*)take(3 * ACC_TOTAL * 8);
    if (cur <= ws_size) break;
    batched = false;
  }
  const int nc = batched ? 3 : 1;

  const int sPartc = batched ? 72 * NB : 0;
  const int sInvc  = batched ? 40 : 0;
  const int sX2c   = batched ? M2 * 128 * 2 : 0;
  const int sX3c   = batched ? M3 * 256 * 2 : 0;
  const int sX4c   = batched ? B * 640 * 2 : 0;
  const int sD2c   = batched ? M2 * 225 : 0;
  const int sD3c   = batched ? M3 * 625 : 0;
  const int sD4c   = batched ? B * 1225 : 0;
  const int sXn2c  = batched ? M2 : 0;
  const int sXn3c  = batched ? M3 : 0;
  const int sXn4c  = batched ? B : 0;

  u16* x2hi = Xbase;   u16* x2lo = Xbase + (size_t)M2 * 128;
  u16* x3hi = Xbase;   u16* x3lo = Xbase + (size_t)M3 * 256;
  u16* x4hi = Xbase;   u16* x4lo = Xbase + (size_t)B * 640;
  u16* Whi2 = Whi;                 u16* Wlo2 = Wlo;                 float* wn2 = wn;
  u16* Whi3 = Whi + 3 * W2SZ;      u16* Wlo3 = Wlo + 3 * W2SZ;      float* wn3 = wn + 3 * 256;
  u16* Whi4 = Whi + 3 * (W2SZ + W3SZ); u16* Wlo4 = Wlo + 3 * (W2SZ + W3SZ);
  float* wn4 = wn + 3 * (256 + 768);

  zero_acc_kernel<<<(3 * ACC_TOTAL + 255) / 256, 256, 0, stream>>>(accd, 3 * ACC_TOTAL);
  w_prep<<<dim3(128, 3),  128, 0, stream>>>(w1, 100, 25,  128, 32,  W1h,  W1l,  w1n);
  w_prep<<<dim3(256, 3),  128, 0, stream>>>(w2, 225, 100, 256, 128, Whi2, Wlo2, wn2);
  w_prep<<<dim3(768, 3),  128, 0, stream>>>(w3, 625, 225, 768, 256, Whi3, Wlo3, wn3);
  w_prep<<<dim3(1280, 3), 128, 0, stream>>>(w4, 1225, 625, 1280, 640, Whi4, Wlo4, wn4);

  for (int c0 = 0; c0 < 3; c0 += nc) {
    // L1 (MFMA two-pass, extraction fused)
    l1_gemm_reduce<<<dim3(NB, nc), 256, 0, stream>>>(
        x, W1h, W1l, w1n, part, NB, c0, sPartc);
    l1_part_fin<<<dim3(36, nc), 256, 0, stream>>>(part, NB, inv36, (double)B * 100.0,
                                                  sPartc, sInvc);
    l1_gemm_sfm<<<dim3(NB, nc), 256, 0, stream>>>(
        x, W1h, W1l, w1n, inv36, cb, x2hi, x2lo, xn, c0, sInvc, sX2c, sXn2c);

    // L2: (M2 x 128) x (256 x 128) -> dist2 (M2 x 225)
    gemm_dist_mfma2<<<dim3(M2 / 256, 1, nc), 512, 0, stream>>>(
        x2hi, x2lo, Whi2, Wlo2, xn, wn2, Sf, 225, 128, accd, ACC_L2, c0,
        sX2c, (int)W2SZ, sXn2c, 256, sD2c);
    l2_sfm<<<dim3(B, 3, nc), 256, 0, stream>>>(
        Sf, accd, (double)M2 * 225.0, cb, x3hi, x3lo, xn, c0, sD2c, sX3c, sXn3c);

    // L3: (M3 x 256) x (768 x 256) -> dist3 (M3 x 625)
    gemm_dist_mfma2<<<dim3(M3 / 256, 3, nc), 512, 0, stream>>>(
        x3hi, x3lo, Whi3, Wlo3, xn, wn3, Sf, 625, 256, accd, ACC_L3, c0,
        sX3c, (int)W3SZ, sXn3c, 768, sD3c);
    l3_sfm<<<dim3(B, nc), 256, 0, stream>>>(
        Sf, accd, (double)M3 * 625.0, cb, x4hi, x4lo, xn, c0, sD3c, sX4c, sXn4c);

    // L4: (B x 640) x (1280 x 640) -> dist4 (B x 1225)
    gemm_dist_mfma2<<<dim3(B / 256, 5, nc), 512, 0, stream>>>(
        x4hi, x4lo, Whi4, Wlo4, xn, wn4, Sf, 1225, 640, accd, ACC_L4, c0,
        sX4c, (int)W4SZ, sXn4c, 1280, sD4c);
    fc_acc<<<B, 128, 0, stream>>>(
        Sf, accd, (double)B * 1225.0, cb, fcw, fcb, out, c0, nc, sD4c);
  }
}